// Round 4
// baseline (181.801 us; speedup 1.0000x reference)
//
#include <hip/hip_runtime.h>

typedef __attribute__((ext_vector_type(4))) float f32x4;
typedef __attribute__((ext_vector_type(8))) short s16x8;

#define C_DIM 256
#define H_DIM 128
#define W_DIM 512
#define HW    (H_DIM * W_DIM)      /* 65536  */
#define CHW   (C_DIM * HW)         /* 16777216 */
#define WS_NEED (2ull * 128 * 512 * 256 * 2)   /* 67108864 B: bf16 [b,h,n,k] */

__device__ __forceinline__ unsigned short f2bf(float f) {
    unsigned u = __builtin_bit_cast(unsigned, f);
    u = (u + 0x7FFFu + ((u >> 16) & 1u)) >> 16;   // round-to-nearest-even
    return (unsigned short)u;
}

// ---------------- K1: transpose+convert img2 -> ws bf16 [b,h][n=512][k=256] ----
// Tile 64c x 64w per WG (256 thr). Read f32 coalesced, LDS staging, write bf16 coalesced.
__global__ __launch_bounds__(256) void transpose_kernel(
    const float* __restrict__ img2, unsigned short* __restrict__ bws)
{
    __shared__ unsigned short tile[64][65];
    const int t = threadIdx.x;
    const int d = blockIdx.x;               // 2*128*8*4 = 8192
    const int cb = d & 3, wb = (d >> 2) & 7, bh = d >> 5;
    const int bb = bh >> 7, hh = bh & 127;
    const float* src = img2 + (size_t)bb * CHW + (size_t)hh * W_DIM
                            + (size_t)(cb * 64) * HW + wb * 64;

    // read: c = t>>2 (0..63), 16 w per thread
    {
        const int c = t >> 2, w0 = (t & 3) << 4;
        const float* p = src + (size_t)c * HW + w0;
        #pragma unroll
        for (int i = 0; i < 16; i += 4) {
            f32x4 v = *(const f32x4*)(p + i);
            #pragma unroll
            for (int j = 0; j < 4; ++j) tile[c][w0 + i + j] = f2bf(v[j]);
        }
    }
    __syncthreads();

    // write: n_l = t>>2 (0..63), 16 c per thread -> out[bh][n][k]
    {
        const int n_l = t >> 2, c4 = (t & 3) << 4;
        unsigned short vals[16];
        #pragma unroll
        for (int i = 0; i < 16; ++i) vals[i] = tile[c4 + i][n_l];
        unsigned short* dst = bws + ((size_t)bh * 512 + wb * 64 + n_l) * 256 + cb * 64 + c4;
        *(s16x8*)(dst)     = *(s16x8*)&vals[0];
        *(s16x8*)(dst + 8) = *(s16x8*)&vals[8];
    }
}

// ---------------- K2: fused costvolume. A: f32->bf16 LDS (once). B: direct bf16 frags
// from ws with explicit 2-stage register prefetch pipeline.
__global__ __launch_bounds__(512, 3) void costvol_kernel(
    const float* __restrict__ img1, const unsigned short* __restrict__ bws,
    const float* __restrict__ intri1,
    const float* __restrict__ extri1, const float* __restrict__ extri2,
    float* __restrict__ out)
{
    __shared__ __align__(16) unsigned char smem[32768];
    unsigned short* Alds = (unsigned short*)smem;  // [64][256] bf16, [m][k], 16B-block XOR swizzle

    const int t = threadIdx.x;
    const int d = blockIdx.x;
    // XCD swizzle: all 8 w1-blocks of one (b,h) land on the same XCD
    const int win = d >> 6, pos = d & 63;
    const int bh    = win * 8 + (pos & 7);
    const int w1blk = pos >> 3;
    const int b = bh >> 7, h = bh & 127;
    const int w1base = w1blk * 64;

    const int wn = t >> 6, lane = t & 63;
    const int lrow = lane & 15, hq = lane >> 4;

    // B fragment pointers into ws: lane covers col n, k = 32*kc + 8*hq + j (16B contiguous)
    const unsigned short* pb[4];
    #pragma unroll
    for (int ct = 0; ct < 4; ++ct)
        pb[ct] = bws + ((size_t)bh * 512 + 64 * wn + 16 * ct + lrow) * 256 + 8 * hq;

    // ---- prologue: issue B loads for kc=0,1 BEFORE A staging (latency hides under it)
    s16x8 breg[2][4];
    #pragma unroll
    for (int ct = 0; ct < 4; ++ct) breg[0][ct] = *(const s16x8*)(pb[ct]);
    #pragma unroll
    for (int ct = 0; ct < 4; ++ct) breg[1][ct] = *(const s16x8*)(pb[ct] + 32);

    // ---- stage A once: rows w1base..+63, all K=256, transposed to [m][k] bf16
    const float* i1 = img1 + (size_t)b * CHW + (size_t)h * W_DIM;
    {
        const int c    = t >> 1;                 // 0..255
        const int wseg = (t & 1) << 5;           // 0 or 32
        const float* src = i1 + (size_t)c * HW + (size_t)(w1base + wseg);
        #pragma unroll
        for (int i0 = 0; i0 < 32; i0 += 4) {
            f32x4 v = *(const f32x4*)(src + i0);
            #pragma unroll
            for (int j = 0; j < 4; ++j) {
                const int w = wseg + i0 + j;
                Alds[w * 256 + ((((c >> 3) ^ (w & 15)) << 3) | (c & 7))] = f2bf(v[j]);
            }
        }
    }
    __syncthreads();

    // A fragment prefetch for kc=0,1
    s16x8 areg[2][4];
    #pragma unroll
    for (int kp = 0; kp < 2; ++kp) {
        #pragma unroll
        for (int rt = 0; rt < 4; ++rt) {
            const int row = 16 * rt + lrow;
            const int kb  = (kp << 2) + hq;
            areg[kp][rt] = *(const s16x8*)&Alds[row * 256 + ((kb ^ (row & 15)) << 3)];
        }
    }

    f32x4 acc[4][4] = {};

    #pragma unroll
    for (int kc = 0; kc < 8; ++kc) {
        const int cur = kc & 1;               // compile-time under full unroll
        // MFMA group on buffers holding kc
        #pragma unroll
        for (int ct = 0; ct < 4; ++ct) {
            #pragma unroll
            for (int rt = 0; rt < 4; ++rt)
                acc[rt][ct] = __builtin_amdgcn_mfma_f32_16x16x32_bf16(
                    areg[cur][rt], breg[cur][ct], acc[rt][ct], 0, 0, 0);
        }
        // refill the just-consumed buffers with kc+2 (issues right after MFMA issue)
        if (kc + 2 < 8) {
            #pragma unroll
            for (int ct = 0; ct < 4; ++ct)
                breg[cur][ct] = *(const s16x8*)(pb[ct] + ((kc + 2) << 5));
            #pragma unroll
            for (int rt = 0; rt < 4; ++rt) {
                const int row = 16 * rt + lrow;
                const int kb  = ((kc + 2) << 2) + hq;
                areg[cur][rt] = *(const s16x8*)&Alds[row * 256 + ((kb ^ (row & 15)) << 3)];
            }
        }
    }

    __syncthreads();   // A LDS dead; reuse for cross-wave reduction

    // ---- epilogue: per-row Se = sum(e), Sei = sum(e*col | col<=w1), Me = max(e | col<=w1)
    // D layout (m89): col = lane&15, row = 4*(lane>>4) + reg
    float (*red)[64][3] = (float(*)[64][3])smem;
    #pragma unroll
    for (int rt = 0; rt < 4; ++rt) {
        #pragma unroll
        for (int r = 0; r < 4; ++r) {
            const int row = 16 * rt + 4 * hq + r;
            const int w1g = w1base + row;
            float Se = 0.f, Sei = 0.f, Me = 0.f;
            #pragma unroll
            for (int ct = 0; ct < 4; ++ct) {
                const int col = 64 * wn + 16 * ct + lrow;
                const float e = __expf(acc[rt][ct][r] * 0.0625f);   // fold 1/sqrt(256)
                Se += e;
                if (col <= w1g) { Sei += e * (float)col; Me = fmaxf(Me, e); }
            }
            #pragma unroll
            for (int m = 1; m < 16; m <<= 1) {
                Se  += __shfl_xor(Se,  m, 64);
                Sei += __shfl_xor(Sei, m, 64);
                Me   = fmaxf(Me, __shfl_xor(Me, m, 64));
            }
            if (lrow == 0) {
                red[wn][row][0] = Se;
                red[wn][row][1] = Sei;
                red[wn][row][2] = Me;
            }
        }
    }
    __syncthreads();

    if (t < 64) {
        const int row = t;
        float Se = 0.f, Sei = 0.f, Me = 0.f;
        #pragma unroll
        for (int q = 0; q < 8; ++q) {
            Se  += red[q][row][0];
            Sei += red[q][row][1];
            Me   = fmaxf(Me, red[q][row][2]);
        }
        const int w1g = w1base + row;
        const float corresp = Sei / Se;            // soft-argmax (masked numerator, full denominator)
        const float conf    = Me / Se;             // max of post-softmax masked prob
        float disp = fabsf(corresp - (float)w1g) * (1.0f / 512.0f);
        disp = fmaxf(disp, 0.1f);
        const float fx = intri1[b * 9];
        const float dx = extri1[b * 16 + 3]  - extri2[b * 16 + 3];
        const float dy = extri1[b * 16 + 7]  - extri2[b * 16 + 7];
        const float dz = extri1[b * 16 + 11] - extri2[b * 16 + 11];
        const float bl = sqrtf(dx * dx + dy * dy + dz * dz);
        const float depth = fx * bl / disp;
        const int oidx = b * HW + h * W_DIM + w1g;
        out[oidx]          = depth;
        out[2 * HW + oidx] = conf;                 // confidence block starts at B*H*W = 131072
    }
}

// ---------------- Fallback (R2 kernel): direct f32 B loads, used only if ws too small
__global__ __launch_bounds__(512, 3) void costvol_fallback(
    const float* __restrict__ img1, const float* __restrict__ img2,
    const float* __restrict__ intri1,
    const float* __restrict__ extri1, const float* __restrict__ extri2,
    float* __restrict__ out)
{
    __shared__ __align__(16) unsigned char smem[32768];
    unsigned short* Alds = (unsigned short*)smem;
    const int t = threadIdx.x;
    const int d = blockIdx.x;
    const int win = d >> 6, pos = d & 63;
    const int bh    = win * 8 + (pos & 7);
    const int w1blk = pos >> 3;
    const int b = bh >> 7, h = bh & 127;
    const int w1base = w1blk * 64;
    const float* i1 = img1 + (size_t)b * CHW + (size_t)h * W_DIM;
    const float* i2 = img2 + (size_t)b * CHW + (size_t)h * W_DIM;
    {
        const int c    = t >> 1;
        const int wseg = (t & 1) << 5;
        const float* src = i1 + (size_t)c * HW + (size_t)(w1base + wseg);
        #pragma unroll
        for (int i0 = 0; i0 < 32; i0 += 4) {
            f32x4 v = *(const f32x4*)(src + i0);
            #pragma unroll
            for (int j = 0; j < 4; ++j) {
                const int w = wseg + i0 + j;
                Alds[w * 256 + ((((c >> 3) ^ (w & 15)) << 3) | (c & 7))] = f2bf(v[j]);
            }
        }
    }
    __syncthreads();
    const int wn = t >> 6, lane = t & 63;
    const int lrow = lane & 15, hq = lane >> 4;
    const float* pb[4];
    #pragma unroll
    for (int ct = 0; ct < 4; ++ct)
        pb[ct] = i2 + (size_t)(8 * hq) * HW + (64 * wn + 16 * ct + lrow);
    f32x4 acc[4][4] = {};
    for (int kc = 0; kc < 8; ++kc) {
        s16x8 afr[4];
        #pragma unroll
        for (int rt = 0; rt < 4; ++rt) {
            const int row = 16 * rt + lrow;
            const int kb  = (kc << 2) + hq;
            afr[rt] = *(const s16x8*)&Alds[row * 256 + ((kb ^ (row & 15)) << 3)];
        }
        #pragma unroll
        for (int ct = 0; ct < 4; ++ct) {
            const float* p = pb[ct] + (size_t)(32 * kc) * HW;
            float f[8];
            #pragma unroll
            for (int j = 0; j < 8; ++j) f[j] = p[(size_t)j * HW];
            s16x8 bfr;
            #pragma unroll
            for (int j = 0; j < 8; ++j) bfr[j] = (short)f2bf(f[j]);
            #pragma unroll
            for (int rt = 0; rt < 4; ++rt)
                acc[rt][ct] = __builtin_amdgcn_mfma_f32_16x16x32_bf16(afr[rt], bfr, acc[rt][ct], 0, 0, 0);
        }
    }
    __syncthreads();
    float (*red)[64][3] = (float(*)[64][3])smem;
    #pragma unroll
    for (int rt = 0; rt < 4; ++rt) {
        #pragma unroll
        for (int r = 0; r < 4; ++r) {
            const int row = 16 * rt + 4 * hq + r;
            const int w1g = w1base + row;
            float Se = 0.f, Sei = 0.f, Me = 0.f;
            #pragma unroll
            for (int ct = 0; ct < 4; ++ct) {
                const int col = 64 * wn + 16 * ct + lrow;
                const float e = __expf(acc[rt][ct][r] * 0.0625f);
                Se += e;
                if (col <= w1g) { Sei += e * (float)col; Me = fmaxf(Me, e); }
            }
            #pragma unroll
            for (int m = 1; m < 16; m <<= 1) {
                Se  += __shfl_xor(Se,  m, 64);
                Sei += __shfl_xor(Sei, m, 64);
                Me   = fmaxf(Me, __shfl_xor(Me, m, 64));
            }
            if (lrow == 0) { red[wn][row][0] = Se; red[wn][row][1] = Sei; red[wn][row][2] = Me; }
        }
    }
    __syncthreads();
    if (t < 64) {
        const int row = t;
        float Se = 0.f, Sei = 0.f, Me = 0.f;
        #pragma unroll
        for (int q = 0; q < 8; ++q) {
            Se += red[q][row][0]; Sei += red[q][row][1]; Me = fmaxf(Me, red[q][row][2]);
        }
        const int w1g = w1base + row;
        const float corresp = Sei / Se;
        const float conf    = Me / Se;
        float disp = fabsf(corresp - (float)w1g) * (1.0f / 512.0f);
        disp = fmaxf(disp, 0.1f);
        const float fx = intri1[b * 9];
        const float dx = extri1[b * 16 + 3]  - extri2[b * 16 + 3];
        const float dy = extri1[b * 16 + 7]  - extri2[b * 16 + 7];
        const float dz = extri1[b * 16 + 11] - extri2[b * 16 + 11];
        const float bl = sqrtf(dx * dx + dy * dy + dz * dz);
        const int oidx = b * HW + h * W_DIM + w1g;
        out[oidx]          = fx * bl / disp;
        out[2 * HW + oidx] = conf;
    }
}

extern "C" void kernel_launch(void* const* d_in, const int* in_sizes, int n_in,
                              void* d_out, int out_size, void* d_ws, size_t ws_size,
                              hipStream_t stream) {
    const float* img1   = (const float*)d_in[0];
    const float* img2   = (const float*)d_in[1];
    const float* intri1 = (const float*)d_in[2];
    const float* extri1 = (const float*)d_in[4];
    const float* extri2 = (const float*)d_in[5];
    if (ws_size >= WS_NEED) {
        unsigned short* bws = (unsigned short*)d_ws;
        transpose_kernel<<<dim3(8192), dim3(256), 0, stream>>>(img2, bws);
        costvol_kernel<<<dim3(2048), dim3(512), 0, stream>>>(
            img1, bws, intri1, extri1, extri2, (float*)d_out);
    } else {
        costvol_fallback<<<dim3(2048), dim3(512), 0, stream>>>(
            img1, img2, intri1, extri1, extri2, (float*)d_out);
    }
}

// Round 6
// 181.621 us; speedup vs baseline: 1.0010x; 1.0010x over previous
//
#include <hip/hip_runtime.h>

typedef __attribute__((ext_vector_type(4))) float f32x4;
typedef __attribute__((ext_vector_type(8))) short s16x8;

#define C_DIM 256
#define H_DIM 128
#define W_DIM 512
#define HW    (H_DIM * W_DIM)      /* 65536  */
#define CHW   (C_DIM * HW)         /* 16777216 */
#define WS_NEED (2ull * 128 * 512 * 256 * 2)   /* 67108864 B: bf16 [b,h,n,k] */

__device__ __forceinline__ unsigned short f2bf(float f) {
    unsigned u = __builtin_bit_cast(unsigned, f);
    u = (u + 0x7FFFu + ((u >> 16) & 1u)) >> 16;   // round-to-nearest-even
    return (unsigned short)u;
}

// ---------------- K1: convert img2 -> ws bf16 [bh][n=512][k=256], LDS-free ----
// Reads: f32x4 per lane, lanes cover contiguous 1KB per instr. Writes: 16B
// k-contiguous per lane; thread covers k0..k0+15 (32B) contiguous over ch=0,1.
__global__ __launch_bounds__(256) void convert_kernel(
    const float* __restrict__ img2, unsigned short* __restrict__ bws)
{
    const int t = threadIdx.x, d = blockIdx.x;   // grid 2048
    const int kq = d & 7, bh = d >> 3;
    const int b = bh >> 7, h = bh & 127;
    const int n0 = 4 * (t & 127);
    const int k0 = kq * 32 + (t >> 7) * 16;
    const float* src = img2 + (size_t)b * CHW + (size_t)h * W_DIM + n0;
    unsigned short* dst = bws + ((size_t)bh * 512 + n0) * 256 + k0;
    #pragma unroll
    for (int ch = 0; ch < 2; ++ch) {
        const int kb = k0 + ch * 8;
        f32x4 v[8];
        #pragma unroll
        for (int j = 0; j < 8; ++j) v[j] = *(const f32x4*)(src + (size_t)(kb + j) * HW);
        #pragma unroll
        for (int nn = 0; nn < 4; ++nn) {
            s16x8 o;
            #pragma unroll
            for (int j = 0; j < 8; ++j) o[j] = (short)f2bf(v[j][nn]);
            *(s16x8*)(dst + (size_t)nn * 256 + ch * 8) = o;
        }
    }
}

// ---------------- K2: swapped-MFMA costvolume. D.row = w2 -> softmax axis lane-local.
__global__ __launch_bounds__(512, 3) void costvol_kernel(
    const float* __restrict__ img1, const unsigned short* __restrict__ bws,
    const float* __restrict__ intri1,
    const float* __restrict__ extri1, const float* __restrict__ extri2,
    float* __restrict__ out)
{
    __shared__ __align__(16) unsigned char smem[32768];
    unsigned short* Alds = (unsigned short*)smem;  // [64][256] bf16, [m][k], 16B-block XOR swizzle

    const int t = threadIdx.x;
    const int d = blockIdx.x;
    // XCD swizzle: all 8 w1-blocks of one (b,h) land on the same XCD
    const int win = d >> 6, pos = d & 63;
    const int bh    = win * 8 + (pos & 7);
    const int w1blk = pos >> 3;
    const int b = bh >> 7, h = bh & 127;
    const int w1base = w1blk * 64;

    // ---- stage A once, scaled by 1/16 (exact in bf16): [m][k] swizzled
    const float* i1 = img1 + (size_t)b * CHW + (size_t)h * W_DIM;
    {
        const int c    = t >> 1;                 // 0..255
        const int wseg = (t & 1) << 5;           // 0 or 32
        const float* src = i1 + (size_t)c * HW + (size_t)(w1base + wseg);
        #pragma unroll
        for (int i0 = 0; i0 < 32; i0 += 4) {
            f32x4 v = *(const f32x4*)(src + i0);
            #pragma unroll
            for (int j = 0; j < 4; ++j) {
                const int w = wseg + i0 + j;
                Alds[w * 256 + ((((c >> 3) ^ (w & 15)) << 3) | (c & 7))] = f2bf(v[j] * 0.0625f);
            }
        }
    }

    const int wn = t >> 6, lane = t & 63;
    const int lrow = lane & 15, hq = lane >> 4;

    // B fragment pointers: lane covers w2 = 64*wn + 16*w2t + lrow, k = 32*kc+8*hq+j
    const unsigned short* pb[4];
    #pragma unroll
    for (int w2t = 0; w2t < 4; ++w2t)
        pb[w2t] = bws + ((size_t)bh * 512 + 64 * wn + 16 * w2t + lrow) * 256 + 8 * hq;

    // prologue: B frags for kc=0 in flight across the staging barrier
    s16x8 bnx[4];
    #pragma unroll
    for (int w2t = 0; w2t < 4; ++w2t) bnx[w2t] = *(const s16x8*)(pb[w2t]);

    __syncthreads();

    f32x4 acc[4][4] = {};   // [w2t][w1t]

    #pragma unroll
    for (int kc = 0; kc < 8; ++kc) {
        s16x8 bcur[4];
        #pragma unroll
        for (int w2t = 0; w2t < 4; ++w2t) bcur[w2t] = bnx[w2t];
        if (kc < 7) {
            #pragma unroll
            for (int w2t = 0; w2t < 4; ++w2t)
                bnx[w2t] = *(const s16x8*)(pb[w2t] + ((kc + 1) << 5));
        }
        s16x8 afr[4];
        #pragma unroll
        for (int w1t = 0; w1t < 4; ++w1t) {
            const int row = 16 * w1t + lrow;
            const int kb  = (kc << 2) + hq;
            afr[w1t] = *(const s16x8*)&Alds[row * 256 + ((kb ^ (row & 15)) << 3)];
        }
        #pragma unroll
        for (int w2t = 0; w2t < 4; ++w2t)
            #pragma unroll
            for (int w1t = 0; w1t < 4; ++w1t)
                acc[w2t][w1t] = __builtin_amdgcn_mfma_f32_16x16x32_bf16(
                    bcur[w2t], afr[w1t], acc[w2t][w1t], 0, 0, 0);
    }

    __syncthreads();   // A LDS dead; reuse for cross-wave reduction

    // ---- epilogue: lane-local over w2 (D.row = w2 = 64*wn + 16*w2t + 4*hq + r,
    //                D.col = w1 = 16*w1t + lrow), then 2-step cross-hq butterfly.
    float (*red)[64][3] = (float(*)[64][3])smem;
    #pragma unroll
    for (int w1t = 0; w1t < 4; ++w1t) {
        const int w1l = 16 * w1t + lrow;
        const int w1g = w1base + w1l;
        float Se = 0.f, Sei = 0.f, Me = 0.f;
        #pragma unroll
        for (int w2t = 0; w2t < 4; ++w2t) {
            #pragma unroll
            for (int r = 0; r < 4; ++r) {
                const int w2 = 64 * wn + 16 * w2t + 4 * hq + r;
                const float e = __expf(acc[w2t][w1t][r]);   // vol already scaled by 1/16
                Se += e;
                if (w2 <= w1g) { Sei += e * (float)w2; Me = fmaxf(Me, e); }
            }
        }
        Se  += __shfl_xor(Se, 16, 64);  Se  += __shfl_xor(Se, 32, 64);
        Sei += __shfl_xor(Sei, 16, 64); Sei += __shfl_xor(Sei, 32, 64);
        Me = fmaxf(Me, __shfl_xor(Me, 16, 64)); Me = fmaxf(Me, __shfl_xor(Me, 32, 64));
        if (hq == 0) {
            red[wn][w1l][0] = Se;
            red[wn][w1l][1] = Sei;
            red[wn][w1l][2] = Me;
        }
    }
    __syncthreads();

    if (t < 64) {
        const int row = t;
        float Se = 0.f, Sei = 0.f, Me = 0.f;
        #pragma unroll
        for (int q = 0; q < 8; ++q) {
            Se  += red[q][row][0];
            Sei += red[q][row][1];
            Me   = fmaxf(Me, red[q][row][2]);
        }
        const int w1g = w1base + row;
        const float corresp = Sei / Se;            // soft-argmax (masked num, full denom)
        const float conf    = Me / Se;             // max of post-softmax masked prob
        float disp = fabsf(corresp - (float)w1g) * (1.0f / 512.0f);
        disp = fmaxf(disp, 0.1f);
        const float fx = intri1[b * 9];
        const float dx = extri1[b * 16 + 3]  - extri2[b * 16 + 3];
        const float dy = extri1[b * 16 + 7]  - extri2[b * 16 + 7];
        const float dz = extri1[b * 16 + 11] - extri2[b * 16 + 11];
        const float bl = sqrtf(dx * dx + dy * dy + dz * dz);
        const float depth = fx * bl / disp;
        const int oidx = b * HW + h * W_DIM + w1g;
        out[oidx]          = depth;
        out[2 * HW + oidx] = conf;                 // confidence block at B*H*W = 131072
    }
}

// ---------------- Fallback (R2 kernel, proven): direct f32 B loads, no ws
__global__ __launch_bounds__(512, 4) void costvol_fallback(
    const float* __restrict__ img1, const float* __restrict__ img2,
    const float* __restrict__ intri1,
    const float* __restrict__ extri1, const float* __restrict__ extri2,
    float* __restrict__ out)
{
    __shared__ __align__(16) unsigned char smem[32768];
    unsigned short* Alds = (unsigned short*)smem;
    const int t = threadIdx.x;
    const int d = blockIdx.x;
    const int win = d >> 6, pos = d & 63;
    const int bh    = win * 8 + (pos & 7);
    const int w1blk = pos >> 3;
    const int b = bh >> 7, h = bh & 127;
    const int w1base = w1blk * 64;
    const float* i1 = img1 + (size_t)b * CHW + (size_t)h * W_DIM;
    const float* i2 = img2 + (size_t)b * CHW + (size_t)h * W_DIM;
    {
        const int c    = t >> 1;
        const int wseg = (t & 1) << 5;
        const float* src = i1 + (size_t)c * HW + (size_t)(w1base + wseg);
        #pragma unroll
        for (int i0 = 0; i0 < 32; i0 += 4) {
            f32x4 v = *(const f32x4*)(src + i0);
            #pragma unroll
            for (int j = 0; j < 4; ++j) {
                const int w = wseg + i0 + j;
                Alds[w * 256 + ((((c >> 3) ^ (w & 15)) << 3) | (c & 7))] = f2bf(v[j]);
            }
        }
    }
    __syncthreads();
    const int wn = t >> 6, lane = t & 63;
    const int lrow = lane & 15, hq = lane >> 4;
    const float* pb[4];
    #pragma unroll
    for (int ct = 0; ct < 4; ++ct)
        pb[ct] = i2 + (size_t)(8 * hq) * HW + (64 * wn + 16 * ct + lrow);
    f32x4 acc[4][4] = {};
    for (int kc = 0; kc < 8; ++kc) {
        s16x8 afr[4];
        #pragma unroll
        for (int rt = 0; rt < 4; ++rt) {
            const int row = 16 * rt + lrow;
            const int kb  = (kc << 2) + hq;
            afr[rt] = *(const s16x8*)&Alds[row * 256 + ((kb ^ (row & 15)) << 3)];
        }
        #pragma unroll
        for (int ct = 0; ct < 4; ++ct) {
            const float* p = pb[ct] + (size_t)(32 * kc) * HW;
            float f[8];
            #pragma unroll
            for (int j = 0; j < 8; ++j) f[j] = p[(size_t)j * HW];
            s16x8 bfr;
            #pragma unroll
            for (int j = 0; j < 8; ++j) bfr[j] = (short)f2bf(f[j]);
            #pragma unroll
            for (int rt = 0; rt < 4; ++rt)
                acc[rt][ct] = __builtin_amdgcn_mfma_f32_16x16x32_bf16(afr[rt], bfr, acc[rt][ct], 0, 0, 0);
        }
    }
    __syncthreads();
    float (*red)[64][3] = (float(*)[64][3])smem;
    #pragma unroll
    for (int rt = 0; rt < 4; ++rt) {
        #pragma unroll
        for (int r = 0; r < 4; ++r) {
            const int row = 16 * rt + 4 * hq + r;
            const int w1g = w1base + row;
            float Se = 0.f, Sei = 0.f, Me = 0.f;
            #pragma unroll
            for (int ct = 0; ct < 4; ++ct) {
                const int col = 64 * wn + 16 * ct + lrow;
                const float e = __expf(acc[rt][ct][r] * 0.0625f);
                Se += e;
                if (col <= w1g) { Sei += e * (float)col; Me = fmaxf(Me, e); }
            }
            #pragma unroll
            for (int m = 1; m < 16; m <<= 1) {
                Se  += __shfl_xor(Se,  m, 64);
                Sei += __shfl_xor(Sei, m, 64);
                Me   = fmaxf(Me, __shfl_xor(Me, m, 64));
            }
            if (lrow == 0) { red[wn][row][0] = Se; red[wn][row][1] = Sei; red[wn][row][2] = Me; }
        }
    }
    __syncthreads();
    if (t < 64) {
        const int row = t;
        float Se = 0.f, Sei = 0.f, Me = 0.f;
        #pragma unroll
        for (int q = 0; q < 8; ++q) {
            Se += red[q][row][0]; Sei += red[q][row][1]; Me = fmaxf(Me, red[q][row][2]);
        }
        const int w1g = w1base + row;
        const float corresp = Sei / Se;
        const float conf    = Me / Se;
        float disp = fabsf(corresp - (float)w1g) * (1.0f / 512.0f);
        disp = fmaxf(disp, 0.1f);
        const float fx = intri1[b * 9];
        const float dx = extri1[b * 16 + 3]  - extri2[b * 16 + 3];
        const float dy = extri1[b * 16 + 7]  - extri2[b * 16 + 7];
        const float dz = extri1[b * 16 + 11] - extri2[b * 16 + 11];
        const float bl = sqrtf(dx * dx + dy * dy + dz * dz);
        const int oidx = b * HW + h * W_DIM + w1g;
        out[oidx]          = fx * bl / disp;
        out[2 * HW + oidx] = conf;
    }
}

extern "C" void kernel_launch(void* const* d_in, const int* in_sizes, int n_in,
                              void* d_out, int out_size, void* d_ws, size_t ws_size,
                              hipStream_t stream) {
    const float* img1   = (const float*)d_in[0];
    const float* img2   = (const float*)d_in[1];
    const float* intri1 = (const float*)d_in[2];
    const float* extri1 = (const float*)d_in[4];
    const float* extri2 = (const float*)d_in[5];
    if (ws_size >= WS_NEED) {
        unsigned short* bws = (unsigned short*)d_ws;
        convert_kernel<<<dim3(2048), dim3(256), 0, stream>>>(img2, bws);
        costvol_kernel<<<dim3(2048), dim3(512), 0, stream>>>(
            img1, bws, intri1, extri1, extri2, (float*)d_out);
    } else {
        costvol_fallback<<<dim3(2048), dim3(512), 0, stream>>>(
            img1, img2, intri1, extri1, extri2, (float*)d_out);
    }
}

// Round 7
// 162.176 us; speedup vs baseline: 1.1210x; 1.1199x over previous
//
#include <hip/hip_runtime.h>
#include <hip/hip_bf16.h>

typedef __attribute__((ext_vector_type(4))) float f32x4;
typedef __attribute__((ext_vector_type(8))) short s16x8;

#define C_DIM 256
#define H_DIM 128
#define W_DIM 512
#define HW    (H_DIM * W_DIM)      /* 65536  */
#define CHW   (C_DIM * HW)         /* 16777216 */

__device__ __forceinline__ unsigned short f2bf(float f) {
    return __builtin_bit_cast(unsigned short, __float2bfloat16(f));
}

// One WG per (b, h, 32-row w1 block): 512 thr = 8 waves, wave grid 1(M=32) x 8(N=64).
// Swapped MFMA: D.row = w2 (softmax axis lane-local), D.col = w1.
// acc = 32 regs/lane; total regs target <=128 => 16 waves/CU (2 WGs resident).
__global__ __launch_bounds__(512, 4) void costvol_kernel(
    const float* __restrict__ img1, const float* __restrict__ img2,
    const float* __restrict__ intri1,
    const float* __restrict__ extri1, const float* __restrict__ extri2,
    float* __restrict__ out)
{
    __shared__ __align__(16) unsigned char smem[16384];
    unsigned short* Alds = (unsigned short*)smem;   // [32][256] bf16, [m][k], 16B-block XOR swizzle

    const int t = threadIdx.x;
    const int d = blockIdx.x;                        // grid 4096
    // XCD swizzle: the 16 WGs sharing (b,h) get ids stride-8 apart -> same XCD (img2 L2 reuse)
    const int pos = d & 127;
    const int bh    = (d >> 7) * 8 + (pos & 7);
    const int w1blk = pos >> 3;                      // 0..15
    const int b = bh >> 7, h = bh & 127;
    const int w1base = w1blk * 32;

    const float* i1 = img1 + (size_t)b * CHW + (size_t)h * W_DIM;
    const float* i2 = img2 + (size_t)b * CHW + (size_t)h * W_DIM;

    // ---- stage A once, scaled by 1/16 (exact): [m=32][k=256] swizzled
    {
        const int c  = t >> 1;                       // 0..255
        const int w0 = (t & 1) << 4;                 // 0 or 16
        const float* src = i1 + (size_t)c * HW + (size_t)(w1base + w0);
        #pragma unroll
        for (int i0 = 0; i0 < 16; i0 += 4) {
            f32x4 v = *(const f32x4*)(src + i0);
            #pragma unroll
            for (int j = 0; j < 4; ++j) {
                const int w = w0 + i0 + j;
                Alds[w * 256 + ((((c >> 3) ^ (w & 15)) << 3) | (c & 7))] = f2bf(v[j] * 0.0625f);
            }
        }
    }
    __syncthreads();

    const int wn = t >> 6, lane = t & 63;
    const int lrow = lane & 15, hq = lane >> 4;

    // B pointers: lane covers w2 = 64*wn + 16*w2t + lrow, k = 32*kc + 8*hq + j
    const float* pb[4];
    #pragma unroll
    for (int w2t = 0; w2t < 4; ++w2t)
        pb[w2t] = i2 + (size_t)(8 * hq) * HW + (64 * wn + 16 * w2t + lrow);

    f32x4 acc[4][2] = {};   // [w2t][w1t]

    for (int kc = 0; kc < 8; ++kc) {
        // A fragments (w1 rows as MFMA B-operand)
        s16x8 afr[2];
        #pragma unroll
        for (int w1t = 0; w1t < 2; ++w1t) {
            const int row = 16 * w1t + lrow;
            const int kb  = (kc << 2) + hq;
            afr[w1t] = *(const s16x8*)&Alds[row * 256 + ((kb ^ (row & 15)) << 3)];
        }
        #pragma unroll
        for (int w2t = 0; w2t < 4; ++w2t) {
            const float* p = pb[w2t] + (size_t)(32 * kc) * HW;
            float f[8];
            #pragma unroll
            for (int j = 0; j < 8; ++j) f[j] = p[(size_t)j * HW];
            s16x8 bfr;
            #pragma unroll
            for (int j = 0; j < 8; ++j) bfr[j] = (short)f2bf(f[j]);
            #pragma unroll
            for (int w1t = 0; w1t < 2; ++w1t)
                acc[w2t][w1t] = __builtin_amdgcn_mfma_f32_16x16x32_bf16(
                    bfr, afr[w1t], acc[w2t][w1t], 0, 0, 0);
        }
    }

    __syncthreads();   // A LDS dead; reuse for cross-wave reduction

    // ---- epilogue: lane-local over w2 (D.row = w2 = 64*wn + 16*w2t + 4*hq + r,
    //                D.col = w1 = 16*w1t + lrow), then 2-step cross-hq butterfly.
    float (*red)[32][3] = (float(*)[32][3])smem;    // [8 waves][32 rows][Se,Sei,Me]
    #pragma unroll
    for (int w1t = 0; w1t < 2; ++w1t) {
        const int w1l = 16 * w1t + lrow;
        const int w1g = w1base + w1l;
        float Se = 0.f, Sei = 0.f, Me = 0.f;
        #pragma unroll
        for (int w2t = 0; w2t < 4; ++w2t) {
            #pragma unroll
            for (int r = 0; r < 4; ++r) {
                const int w2 = 64 * wn + 16 * w2t + 4 * hq + r;
                const float e = __expf(acc[w2t][w1t][r]);   // vol pre-scaled by 1/16
                Se += e;
                if (w2 <= w1g) { Sei += e * (float)w2; Me = fmaxf(Me, e); }
            }
        }
        Se  += __shfl_xor(Se, 16, 64);  Se  += __shfl_xor(Se, 32, 64);
        Sei += __shfl_xor(Sei, 16, 64); Sei += __shfl_xor(Sei, 32, 64);
        Me = fmaxf(Me, __shfl_xor(Me, 16, 64)); Me = fmaxf(Me, __shfl_xor(Me, 32, 64));
        if (hq == 0) {
            red[wn][w1l][0] = Se;
            red[wn][w1l][1] = Sei;
            red[wn][w1l][2] = Me;
        }
    }
    __syncthreads();

    if (t < 32) {
        const int row = t;
        float Se = 0.f, Sei = 0.f, Me = 0.f;
        #pragma unroll
        for (int q = 0; q < 8; ++q) {
            Se  += red[q][row][0];
            Sei += red[q][row][1];
            Me   = fmaxf(Me, red[q][row][2]);
        }
        const int w1g = w1base + row;
        const float corresp = Sei / Se;            // soft-argmax (masked num, full denom)
        const float conf    = Me / Se;             // max of post-softmax masked prob
        float disp = fabsf(corresp - (float)w1g) * (1.0f / 512.0f);
        disp = fmaxf(disp, 0.1f);
        const float fx = intri1[b * 9];
        const float dx = extri1[b * 16 + 3]  - extri2[b * 16 + 3];
        const float dy = extri1[b * 16 + 7]  - extri2[b * 16 + 7];
        const float dz = extri1[b * 16 + 11] - extri2[b * 16 + 11];
        const float bl = sqrtf(dx * dx + dy * dy + dz * dz);
        const float depth = fx * bl / disp;
        const int oidx = b * HW + h * W_DIM + w1g;
        out[oidx]          = depth;
        out[2 * HW + oidx] = conf;                 // confidence block at B*H*W = 131072
    }
}

extern "C" void kernel_launch(void* const* d_in, const int* in_sizes, int n_in,
                              void* d_out, int out_size, void* d_ws, size_t ws_size,
                              hipStream_t stream) {
    const float* img1   = (const float*)d_in[0];
    const float* img2   = (const float*)d_in[1];
    const float* intri1 = (const float*)d_in[2];
    const float* extri1 = (const float*)d_in[4];
    const float* extri2 = (const float*)d_in[5];
    costvol_kernel<<<dim3(4096), dim3(512), 0, stream>>>(
        img1, img2, intri1, extri1, extri2, (float*)d_out);
}

// Round 8
// 141.818 us; speedup vs baseline: 1.2819x; 1.1436x over previous
//
#include <hip/hip_runtime.h>
#include <hip/hip_bf16.h>

typedef __attribute__((ext_vector_type(4))) float f32x4;
typedef __attribute__((ext_vector_type(8))) short s16x8;

#define C_DIM 256
#define H_DIM 128
#define W_DIM 512
#define HW    (H_DIM * W_DIM)      /* 65536  */
#define CHW   (C_DIM * HW)         /* 16777216 */
#define WS_NEED (2ull * 128 * 512 * 256 * 2)   /* 67108864 B: bf16 [bh][n][k] */

__device__ __forceinline__ unsigned short f2bf(float f) {
    return __builtin_bit_cast(unsigned short, __float2bfloat16(f));
}

__device__ __forceinline__ void gl_lds16(const void* g, void* l) {
    __builtin_amdgcn_global_load_lds(
        (const __attribute__((address_space(1))) void*)g,
        (__attribute__((address_space(3))) void*)l, 16, 0, 0);
}

// ---------------- K1: transpose+convert img2 -> ws bf16 [bh][n=512][k=256] ----
// (R3 structure, batch-stride FIXED). 64c x 64w tile per WG, LDS staged.
__global__ __launch_bounds__(256) void transpose_kernel(
    const float* __restrict__ img2, unsigned short* __restrict__ bws)
{
    __shared__ unsigned short tile[64][65];
    const int t = threadIdx.x;
    const int d = blockIdx.x;               // 8192 = 2b*128h*4cb*8wb
    const int cb = d & 3, wb = (d >> 2) & 7, bh = d >> 5;
    const int b = bh >> 7, h = bh & 127;
    const float* src = img2 + (size_t)b * CHW + (size_t)h * W_DIM
                            + (size_t)(cb * 64) * HW + wb * 64;
    {
        const int c = t >> 2, w0 = (t & 3) << 4;
        const float* p = src + (size_t)c * HW + w0;
        #pragma unroll
        for (int i = 0; i < 16; i += 4) {
            f32x4 v = *(const f32x4*)(p + i);
            #pragma unroll
            for (int j = 0; j < 4; ++j) tile[c][w0 + i + j] = f2bf(v[j]);
        }
    }
    __syncthreads();
    {
        const int n_l = t >> 2, c4 = (t & 3) << 4;
        unsigned short vals[16];
        #pragma unroll
        for (int i = 0; i < 16; ++i) vals[i] = tile[c4 + i][n_l];
        unsigned short* dst = bws + ((size_t)bh * 512 + wb * 64 + n_l) * 256 + cb * 64 + c4;
        *(s16x8*)(dst)     = *(s16x8*)&vals[0];
        *(s16x8*)(dst + 8) = *(s16x8*)&vals[8];
    }
}

// ---------------- K2: m97-style. A: f32->bf16 LDS once. B: global_load_lds dbuf, BK=32.
// Swapped MFMA (D.row = w2): lane-local softmax axis.
__global__ __launch_bounds__(512, 2) void costvol_kernel(
    const float* __restrict__ img1, const unsigned short* __restrict__ bws,
    const float* __restrict__ intri1,
    const float* __restrict__ extri1, const float* __restrict__ extri2,
    float* __restrict__ out)
{
    __shared__ __align__(16) unsigned char smem[98304];   // A 32K | B0 32K | B1 32K
    unsigned short* Alds = (unsigned short*)smem;         // [64][256] bf16 swizzled

    const int t = threadIdx.x;
    const int d = blockIdx.x;
    // XCD swizzle: the 8 WGs sharing (b,h) get ids stride-8 apart -> same XCD
    const int win = d >> 6, pos = d & 63;
    const int bh    = win * 8 + (pos & 7);
    const int w1blk = pos >> 3;
    const int b = bh >> 7, h = bh & 127;
    const int w1base = w1blk * 64;

    const int wv = t >> 6, lane = t & 63;
    const int lrow = lane & 15, hq = lane >> 4;

    // ---- B staging setup: wave wv instr i covers rows n = (wv*4+i)*16 + (lane>>2),
    //      k8 = lane&3 (16B unit). Source pre-swizzled: k8 ^ ((n>>1)&3)  [m173 pattern]
    const int n_st  = (lane >> 2);            // row within 16-row group
    const int k8_st = lane & 3;
    const unsigned short* bsrc[4];
    #pragma unroll
    for (int i = 0; i < 4; ++i) {
        const int n = (wv * 4 + i) * 16 + n_st;
        bsrc[i] = bws + ((size_t)bh * 512 + n) * 256 + 8 * (k8_st ^ ((n >> 1) & 3));
    }

    // prologue: issue B stage for kc=0 (in flight under A staging)
    #pragma unroll
    for (int i = 0; i < 4; ++i)
        gl_lds16(bsrc[i], smem + 32768 + (wv * 4 + i) * 1024);

    // ---- stage A once, scaled by 1/16: [m=64][k=256], 16B-block XOR swizzle
    const float* i1 = img1 + (size_t)b * CHW + (size_t)h * W_DIM;
    {
        const int c    = t >> 1;                 // 0..255
        const int wseg = (t & 1) << 5;           // 0 or 32
        const float* src = i1 + (size_t)c * HW + (size_t)(w1base + wseg);
        #pragma unroll
        for (int i0 = 0; i0 < 32; i0 += 4) {
            f32x4 v = *(const f32x4*)(src + i0);
            #pragma unroll
            for (int j = 0; j < 4; ++j) {
                const int w = wseg + i0 + j;
                Alds[w * 256 + ((((c >> 3) ^ (w & 15)) << 3) | (c & 7))] = f2bf(v[j] * 0.0625f);
            }
        }
    }
    __syncthreads();   // drains vmcnt too: B buf0 ready

    const int wn = wv;   // wave covers w2 in [64*wn, 64*wn+64), all 64 w1
    f32x4 acc[4][4] = {};   // [w2t][w1t]

    // per-lane B read offsets (bytes) within a B buffer, for the 4 w2t frags
    int boff[4];
    #pragma unroll
    for (int w2t = 0; w2t < 4; ++w2t) {
        const int n = 64 * wn + 16 * w2t + lrow;
        boff[w2t] = n * 64 + 16 * (hq ^ ((n >> 1) & 3));
    }

    #pragma unroll
    for (int kc = 0; kc < 8; ++kc) {
        // issue next-step staging into the other buffer
        if (kc < 7) {
            const int nb = (kc + 1) & 1;
            #pragma unroll
            for (int i = 0; i < 4; ++i)
                gl_lds16(bsrc[i] + (kc + 1) * 32, smem + 32768 + nb * 32768 + (wv * 4 + i) * 1024);
        }
        const unsigned char* Bbuf = smem + 32768 + (kc & 1) * 32768;
        // A fragments (w1 rows), k = kc*32 + 8*hq + j
        s16x8 afr[4];
        #pragma unroll
        for (int w1t = 0; w1t < 4; ++w1t) {
            const int row = 16 * w1t + lrow;
            const int kb  = (kc << 2) + hq;
            afr[w1t] = *(const s16x8*)&Alds[row * 256 + ((kb ^ (row & 15)) << 3)];
        }
        // B fragments (w2 rows) + MFMA
        #pragma unroll
        for (int w2t = 0; w2t < 4; ++w2t) {
            const s16x8 bfr = *(const s16x8*)(Bbuf + boff[w2t]);
            #pragma unroll
            for (int w1t = 0; w1t < 4; ++w1t)
                acc[w2t][w1t] = __builtin_amdgcn_mfma_f32_16x16x32_bf16(
                    bfr, afr[w1t], acc[w2t][w1t], 0, 0, 0);
        }
        __syncthreads();
    }

    // ---- epilogue: lane-local over w2 (D.row = w2 = 64*wn + 16*w2t + 4*hq + r,
    //                D.col = w1 = 16*w1t + lrow), 2-step cross-hq butterfly.
    float (*red)[64][3] = (float(*)[64][3])smem;   // aliases A region (dead)
    #pragma unroll
    for (int w1t = 0; w1t < 4; ++w1t) {
        const int w1l = 16 * w1t + lrow;
        const int w1g = w1base + w1l;
        float Se = 0.f, Sei = 0.f, Me = 0.f;
        #pragma unroll
        for (int w2t = 0; w2t < 4; ++w2t) {
            #pragma unroll
            for (int r = 0; r < 4; ++r) {
                const int w2 = 64 * wn + 16 * w2t + 4 * hq + r;
                const float e = __expf(acc[w2t][w1t][r]);   // vol pre-scaled by 1/16
                Se += e;
                if (w2 <= w1g) { Sei += e * (float)w2; Me = fmaxf(Me, e); }
            }
        }
        Se  += __shfl_xor(Se, 16, 64);  Se  += __shfl_xor(Se, 32, 64);
        Sei += __shfl_xor(Sei, 16, 64); Sei += __shfl_xor(Sei, 32, 64);
        Me = fmaxf(Me, __shfl_xor(Me, 16, 64)); Me = fmaxf(Me, __shfl_xor(Me, 32, 64));
        if (hq == 0) {
            red[wn][w1l][0] = Se;
            red[wn][w1l][1] = Sei;
            red[wn][w1l][2] = Me;
        }
    }
    __syncthreads();

    if (t < 64) {
        const int row = t;
        float Se = 0.f, Sei = 0.f, Me = 0.f;
        #pragma unroll
        for (int q = 0; q < 8; ++q) {
            Se  += red[q][row][0];
            Sei += red[q][row][1];
            Me   = fmaxf(Me, red[q][row][2]);
        }
        const int w1g = w1base + row;
        const float corresp = Sei / Se;            // soft-argmax (masked num, full denom)
        const float conf    = Me / Se;             // max of post-softmax masked prob
        float disp = fabsf(corresp - (float)w1g) * (1.0f / 512.0f);
        disp = fmaxf(disp, 0.1f);
        const float fx = intri1[b * 9];
        const float dx = extri1[b * 16 + 3]  - extri2[b * 16 + 3];
        const float dy = extri1[b * 16 + 7]  - extri2[b * 16 + 7];
        const float dz = extri1[b * 16 + 11] - extri2[b * 16 + 11];
        const float bl = sqrtf(dx * dx + dy * dy + dz * dz);
        const float depth = fx * bl / disp;
        const int oidx = b * HW + h * W_DIM + w1g;
        out[oidx]          = depth;
        out[2 * HW + oidx] = conf;                 // confidence block at B*H*W = 131072
    }
}

// ---------------- Fallback (R2 kernel, proven): direct f32 B loads, no ws
__global__ __launch_bounds__(512, 4) void costvol_fallback(
    const float* __restrict__ img1, const float* __restrict__ img2,
    const float* __restrict__ intri1,
    const float* __restrict__ extri1, const float* __restrict__ extri2,
    float* __restrict__ out)
{
    __shared__ __align__(16) unsigned char smem[32768];
    unsigned short* Alds = (unsigned short*)smem;
    const int t = threadIdx.x;
    const int d = blockIdx.x;
    const int win = d >> 6, pos = d & 63;
    const int bh    = win * 8 + (pos & 7);
    const int w1blk = pos >> 3;
    const int b = bh >> 7, h = bh & 127;
    const int w1base = w1blk * 64;
    const float* i1 = img1 + (size_t)b * CHW + (size_t)h * W_DIM;
    const float* i2 = img2 + (size_t)b * CHW + (size_t)h * W_DIM;
    {
        const int c    = t >> 1;
        const int wseg = (t & 1) << 5;
        const float* src = i1 + (size_t)c * HW + (size_t)(w1base + wseg);
        #pragma unroll
        for (int i0 = 0; i0 < 32; i0 += 4) {
            f32x4 v = *(const f32x4*)(src + i0);
            #pragma unroll
            for (int j = 0; j < 4; ++j) {
                const int w = wseg + i0 + j;
                Alds[w * 256 + ((((c >> 3) ^ (w & 15)) << 3) | (c & 7))] = f2bf(v[j]);
            }
        }
    }
    __syncthreads();
    const int wn = t >> 6, lane = t & 63;
    const int lrow = lane & 15, hq = lane >> 4;
    const float* pb[4];
    #pragma unroll
    for (int ct = 0; ct < 4; ++ct)
        pb[ct] = i2 + (size_t)(8 * hq) * HW + (64 * wn + 16 * ct + lrow);
    f32x4 acc[4][4] = {};
    for (int kc = 0; kc < 8; ++kc) {
        s16x8 afr[4];
        #pragma unroll
        for (int rt = 0; rt < 4; ++rt) {
            const int row = 16 * rt + lrow;
            const int kb  = (kc << 2) + hq;
            afr[rt] = *(const s16x8*)&Alds[row * 256 + ((kb ^ (row & 15)) << 3)];
        }
        #pragma unroll
        for (int ct = 0; ct < 4; ++ct) {
            const float* p = pb[ct] + (size_t)(32 * kc) * HW;
            float f[8];
            #pragma unroll
            for (int j = 0; j < 8; ++j) f[j] = p[(size_t)j * HW];
            s16x8 bfr;
            #pragma unroll
            for (int j = 0; j < 8; ++j) bfr[j] = (short)f2bf(f[j]);
            #pragma unroll
            for (int rt = 0; rt < 4; ++rt)
                acc[rt][ct] = __builtin_amdgcn_mfma_f32_16x16x32_bf16(afr[rt], bfr, acc[rt][ct], 0, 0, 0);
        }
    }
    __syncthreads();
    float (*red)[64][3] = (float(*)[64][3])smem;
    #pragma unroll
    for (int rt = 0; rt < 4; ++rt) {
        #pragma unroll
        for (int r = 0; r < 4; ++r) {
            const int row = 16 * rt + 4 * hq + r;
            const int w1g = w1base + row;
            float Se = 0.f, Sei = 0.f, Me = 0.f;
            #pragma unroll
            for (int ct = 0; ct < 4; ++ct) {
                const int col = 64 * wn + 16 * ct + lrow;
                const float e = __expf(acc[rt][ct][r] * 0.0625f);
                Se += e;
                if (col <= w1g) { Sei += e * (float)col; Me = fmaxf(Me, e); }
            }
            #pragma unroll
            for (int m = 1; m < 16; m <<= 1) {
                Se  += __shfl_xor(Se,  m, 64);
                Sei += __shfl_xor(Sei, m, 64);
                Me   = fmaxf(Me, __shfl_xor(Me, m, 64));
            }
            if (lrow == 0) { red[wn][row][0] = Se; red[wn][row][1] = Sei; red[wn][row][2] = Me; }
        }
    }
    __syncthreads();
    if (t < 64) {
        const int row = t;
        float Se = 0.f, Sei = 0.f, Me = 0.f;
        #pragma unroll
        for (int q = 0; q < 8; ++q) {
            Se += red[q][row][0]; Sei += red[q][row][1]; Me = fmaxf(Me, red[q][row][2]);
        }
        const int w1g = w1base + row;
        const float corresp = Sei / Se;
        const float conf    = Me / Se;
        float disp = fabsf(corresp - (float)w1g) * (1.0f / 512.0f);
        disp = fmaxf(disp, 0.1f);
        const float fx = intri1[b * 9];
        const float dx = extri1[b * 16 + 3]  - extri2[b * 16 + 3];
        const float dy = extri1[b * 16 + 7]  - extri2[b * 16 + 7];
        const float dz = extri1[b * 16 + 11] - extri2[b * 16 + 11];
        const float bl = sqrtf(dx * dx + dy * dy + dz * dz);
        const int oidx = b * HW + h * W_DIM + w1g;
        out[oidx]          = fx * bl / disp;
        out[2 * HW + oidx] = conf;
    }
}

extern "C" void kernel_launch(void* const* d_in, const int* in_sizes, int n_in,
                              void* d_out, int out_size, void* d_ws, size_t ws_size,
                              hipStream_t stream) {
    const float* img1   = (const float*)d_in[0];
    const float* img2   = (const float*)d_in[1];
    const float* intri1 = (const float*)d_in[2];
    const float* extri1 = (const float*)d_in[4];
    const float* extri2 = (const float*)d_in[5];
    if (ws_size >= WS_NEED) {
        unsigned short* bws = (unsigned short*)d_ws;
        transpose_kernel<<<dim3(8192), dim3(256), 0, stream>>>(img2, bws);
        costvol_kernel<<<dim3(2048), dim3(512), 0, stream>>>(
            img1, bws, intri1, extri1, extri2, (float*)d_out);
    } else {
        costvol_fallback<<<dim3(2048), dim3(512), 0, stream>>>(
            img1, img2, intri1, extri1, extri2, (float*)d_out);
    }
}

// Round 9
// 123.733 us; speedup vs baseline: 1.4693x; 1.1462x over previous
//
#include <hip/hip_runtime.h>
#include <hip/hip_bf16.h>

typedef __attribute__((ext_vector_type(4))) float f32x4;
typedef __attribute__((ext_vector_type(8))) short s16x8;

#define C_DIM 256
#define H_DIM 128
#define W_DIM 512
#define HW    (H_DIM * W_DIM)      /* 65536  */
#define CHW   (C_DIM * HW)         /* 16777216 */
#define WS_NEED (2ull * 128 * 512 * 256 * 2)   /* 67108864 B: bf16 [bh][n][k] */

__device__ __forceinline__ unsigned short f2bf(float f) {
    return __builtin_bit_cast(unsigned short, __float2bfloat16(f));
}

__device__ __forceinline__ void gl_lds16(const void* g, void* l) {
    __builtin_amdgcn_global_load_lds(
        (const __attribute__((address_space(1))) void*)g,
        (__attribute__((address_space(3))) void*)l, 16, 0, 0);
}

// ---------------- K1: transpose+convert img2 -> ws bf16 [bh][n=512][k=256] ----
__global__ __launch_bounds__(256) void transpose_kernel(
    const float* __restrict__ img2, unsigned short* __restrict__ bws)
{
    __shared__ unsigned short tile[64][65];
    const int t = threadIdx.x;
    const int d = blockIdx.x;               // 8192 = 2b*128h*4cb*8wb
    const int cb = d & 3, wb = (d >> 2) & 7, bh = d >> 5;
    const int b = bh >> 7, h = bh & 127;
    const float* src = img2 + (size_t)b * CHW + (size_t)h * W_DIM
                            + (size_t)(cb * 64) * HW + wb * 64;
    {
        const int c = t >> 2, w0 = (t & 3) << 4;
        const float* p = src + (size_t)c * HW + w0;
        #pragma unroll
        for (int i = 0; i < 16; i += 4) {
            f32x4 v = *(const f32x4*)(p + i);
            #pragma unroll
            for (int j = 0; j < 4; ++j) tile[c][w0 + i + j] = f2bf(v[j]);
        }
    }
    __syncthreads();
    {
        const int n_l = t >> 2, c4 = (t & 3) << 4;
        unsigned short vals[16];
        #pragma unroll
        for (int i = 0; i < 16; ++i) vals[i] = tile[c4 + i][n_l];
        unsigned short* dst = bws + ((size_t)bh * 512 + wb * 64 + n_l) * 256 + cb * 64 + c4;
        *(s16x8*)(dst)     = *(s16x8*)&vals[0];
        *(s16x8*)(dst + 8) = *(s16x8*)&vals[8];
    }
}

// ---------------- K2: 1024-thr WG = 128 w1 x 512 w2. B via global_load_lds dbuf BK=32.
// Swapped MFMA (D.row = w2): softmax axis lane-local. Wave = 32 w2 x 128 w1.
__global__ __launch_bounds__(1024, 4) void costvol_kernel(
    const float* __restrict__ img1, const unsigned short* __restrict__ bws,
    const float* __restrict__ intri1,
    const float* __restrict__ extri1, const float* __restrict__ extri2,
    float* __restrict__ out)
{
    __shared__ __align__(16) unsigned char smem[131072];  // A 64K | B0 32K | B1 32K
    unsigned short* Alds = (unsigned short*)smem;         // [128][256] bf16 swizzled

    const int t = threadIdx.x;
    const int d = blockIdx.x;                              // grid 1024
    // XCD swizzle: the 4 WGs sharing (b,h) get ids stride-8 apart -> same XCD
    const int pos = d & 31;
    const int bh    = (d >> 5) * 8 + (pos & 7);
    const int w1blk = pos >> 3;                            // 0..3
    const int b = bh >> 7, h = bh & 127;
    const int w1base = w1blk * 128;

    const int wv = t >> 6, lane = t & 63;
    const int lrow = lane & 15, hq = lane >> 4;

    // ---- B staging: tile [n=512][k=32] bf16 = 32KB = 2048 16B-units. Thread covers
    // units u = t and t+1024; instr i: wave-uniform LDS base i*16384 + wv*1024.
    // Source pre-swizzled k8 ^ ((n>>1)&3)  [m173 pattern].
    const unsigned short* bsrc[2];
    #pragma unroll
    for (int i = 0; i < 2; ++i) {
        const int u  = t + i * 1024;
        const int n  = u >> 2, k8 = u & 3;
        bsrc[i] = bws + ((size_t)bh * 512 + n) * 256 + 8 * (k8 ^ ((n >> 1) & 3));
    }

    // prologue: issue B stage for kc=0 (in flight under A staging)
    #pragma unroll
    for (int i = 0; i < 2; ++i)
        gl_lds16(bsrc[i], smem + 65536 + i * 16384 + wv * 1024);

    // ---- stage A once, scaled by 1/16: [m=128][k=256], 16B-block XOR swizzle
    const float* i1 = img1 + (size_t)b * CHW + (size_t)h * W_DIM;
    {
        const int c  = t >> 2;                   // 0..255
        const int w0 = (t & 3) << 5;             // 0,32,64,96
        const float* src = i1 + (size_t)c * HW + (size_t)(w1base + w0);
        #pragma unroll
        for (int i0 = 0; i0 < 32; i0 += 4) {
            f32x4 v = *(const f32x4*)(src + i0);
            #pragma unroll
            for (int j = 0; j < 4; ++j) {
                const int w = w0 + i0 + j;
                Alds[w * 256 + ((((c >> 3) ^ (w & 15)) << 3) | (c & 7))] = f2bf(v[j] * 0.0625f);
            }
        }
    }
    __syncthreads();   // drains vmcnt too: B buf0 ready

    f32x4 acc[2][8] = {};   // [w2t][w1t]

    // per-lane B read offsets (bytes) within a B buffer
    int boff[2];
    #pragma unroll
    for (int w2t = 0; w2t < 2; ++w2t) {
        const int n = 32 * wv + 16 * w2t + lrow;
        boff[w2t] = n * 64 + 16 * (hq ^ ((n >> 1) & 3));
    }

    #pragma unroll
    for (int kc = 0; kc < 8; ++kc) {
        if (kc < 7) {
            const int nb = (kc + 1) & 1;
            #pragma unroll
            for (int i = 0; i < 2; ++i)
                gl_lds16(bsrc[i] + (kc + 1) * 32, smem + 65536 + nb * 32768 + i * 16384 + wv * 1024);
        }
        const unsigned char* Bbuf = smem + 65536 + (kc & 1) * 32768;
        s16x8 bfr[2];
        #pragma unroll
        for (int w2t = 0; w2t < 2; ++w2t)
            bfr[w2t] = *(const s16x8*)(Bbuf + boff[w2t]);
        #pragma unroll
        for (int w1t = 0; w1t < 8; ++w1t) {
            const int row = 16 * w1t + lrow;
            const int kb  = (kc << 2) + hq;
            const s16x8 afr = *(const s16x8*)&Alds[row * 256 + ((kb ^ (row & 15)) << 3)];
            #pragma unroll
            for (int w2t = 0; w2t < 2; ++w2t)
                acc[w2t][w1t] = __builtin_amdgcn_mfma_f32_16x16x32_bf16(
                    bfr[w2t], afr, acc[w2t][w1t], 0, 0, 0);
        }
        __syncthreads();
    }

    // ---- epilogue: lane-local over w2 (w2 = 32*wv + 16*w2t + 4*hq + r, w1 = 16*w1t + lrow)
    float (*red)[128][3] = (float(*)[128][3])smem;   // [16 waves][128 rows][Se,Sei,Me], aliases A
    #pragma unroll
    for (int w1t = 0; w1t < 8; ++w1t) {
        const int w1l = 16 * w1t + lrow;
        const int w1g = w1base + w1l;
        float Se = 0.f, Sei = 0.f, Me = 0.f;
        #pragma unroll
        for (int w2t = 0; w2t < 2; ++w2t) {
            #pragma unroll
            for (int r = 0; r < 4; ++r) {
                const int w2 = 32 * wv + 16 * w2t + 4 * hq + r;
                const float e = __expf(acc[w2t][w1t][r]);   // vol pre-scaled by 1/16
                Se += e;
                if (w2 <= w1g) { Sei += e * (float)w2; Me = fmaxf(Me, e); }
            }
        }
        Se  += __shfl_xor(Se, 16, 64);  Se  += __shfl_xor(Se, 32, 64);
        Sei += __shfl_xor(Sei, 16, 64); Sei += __shfl_xor(Sei, 32, 64);
        Me = fmaxf(Me, __shfl_xor(Me, 16, 64)); Me = fmaxf(Me, __shfl_xor(Me, 32, 64));
        if (hq == 0) {
            red[wv][w1l][0] = Se;
            red[wv][w1l][1] = Sei;
            red[wv][w1l][2] = Me;
        }
    }
    __syncthreads();

    if (t < 128) {
        const int row = t;
        float Se = 0.f, Sei = 0.f, Me = 0.f;
        #pragma unroll
        for (int q = 0; q < 16; ++q) {
            Se  += red[q][row][0];
            Sei += red[q][row][1];
            Me   = fmaxf(Me, red[q][row][2]);
        }
        const int w1g = w1base + row;
        const float corresp = Sei / Se;            // soft-argmax (masked num, full denom)
        const float conf    = Me / Se;             // max of post-softmax masked prob
        float disp = fabsf(corresp - (float)w1g) * (1.0f / 512.0f);
        disp = fmaxf(disp, 0.1f);
        const float fx = intri1[b * 9];
        const float dx = extri1[b * 16 + 3]  - extri2[b * 16 + 3];
        const float dy = extri1[b * 16 + 7]  - extri2[b * 16 + 7];
        const float dz = extri1[b * 16 + 11] - extri2[b * 16 + 11];
        const float bl = sqrtf(dx * dx + dy * dy + dz * dz);
        const float depth = fx * bl / disp;
        const int oidx = b * HW + h * W_DIM + w1g;
        out[oidx]          = depth;
        out[2 * HW + oidx] = conf;                 // confidence block at B*H*W = 131072
    }
}

// ---------------- Fallback (R2 kernel, proven): direct f32 B loads, no ws
__global__ __launch_bounds__(512, 4) void costvol_fallback(
    const float* __restrict__ img1, const float* __restrict__ img2,
    const float* __restrict__ intri1,
    const float* __restrict__ extri1, const float* __restrict__ extri2,
    float* __restrict__ out)
{
    __shared__ __align__(16) unsigned char smem[32768];
    unsigned short* Alds = (unsigned short*)smem;
    const int t = threadIdx.x;
    const int d = blockIdx.x;
    const int win = d >> 6, pos = d & 63;
    const int bh    = win * 8 + (pos & 7);
    const int w1blk = pos >> 3;
    const int b = bh >> 7, h = bh & 127;
    const int w1base = w1blk * 64;
    const float* i1 = img1 + (size_t)b * CHW + (size_t)h * W_DIM;
    const float* i2 = img2 + (size_t)b * CHW + (size_t)h * W_DIM;
    {
        const int c    = t >> 1;
        const int wseg = (t & 1) << 5;
        const float* src = i1 + (size_t)c * HW + (size_t)(w1base + wseg);
        #pragma unroll
        for (int i0 = 0; i0 < 32; i0 += 4) {
            f32x4 v = *(const f32x4*)(src + i0);
            #pragma unroll
            for (int j = 0; j < 4; ++j) {
                const int w = wseg + i0 + j;
                Alds[w * 256 + ((((c >> 3) ^ (w & 15)) << 3) | (c & 7))] = f2bf(v[j]);
            }
        }
    }
    __syncthreads();
    const int wn = t >> 6, lane = t & 63;
    const int lrow = lane & 15, hq = lane >> 4;
    const float* pb[4];
    #pragma unroll
    for (int ct = 0; ct < 4; ++ct)
        pb[ct] = i2 + (size_t)(8 * hq) * HW + (64 * wn + 16 * ct + lrow);
    f32x4 acc[4][4] = {};
    for (int kc = 0; kc < 8; ++kc) {
        s16x8 afr[4];
        #pragma unroll
        for (int rt = 0; rt < 4; ++rt) {
            const int row = 16 * rt + lrow;
            const int kb  = (kc << 2) + hq;
            afr[rt] = *(const s16x8*)&Alds[row * 256 + ((kb ^ (row & 15)) << 3)];
        }
        #pragma unroll
        for (int ct = 0; ct < 4; ++ct) {
            const float* p = pb[ct] + (size_t)(32 * kc) * HW;
            float f[8];
            #pragma unroll
            for (int j = 0; j < 8; ++j) f[j] = p[(size_t)j * HW];
            s16x8 bfr;
            #pragma unroll
            for (int j = 0; j < 8; ++j) bfr[j] = (short)f2bf(f[j]);
            #pragma unroll
            for (int rt = 0; rt < 4; ++rt)
                acc[rt][ct] = __builtin_amdgcn_mfma_f32_16x16x32_bf16(afr[rt], bfr, acc[rt][ct], 0, 0, 0);
        }
    }
    __syncthreads();
    float (*red)[64][3] = (float(*)[64][3])smem;
    #pragma unroll
    for (int rt = 0; rt < 4; ++rt) {
        #pragma unroll
        for (int r = 0; r < 4; ++r) {
            const int row = 16 * rt + 4 * hq + r;
            const int w1g = w1base + row;
            float Se = 0.f, Sei = 0.f, Me = 0.f;
            #pragma unroll
            for (int ct = 0; ct < 4; ++ct) {
                const int col = 64 * wn + 16 * ct + lrow;
                const float e = __expf(acc[rt][ct][r] * 0.0625f);
                Se += e;
                if (col <= w1g) { Sei += e * (float)col; Me = fmaxf(Me, e); }
            }
            #pragma unroll
            for (int m = 1; m < 16; m <<= 1) {
                Se  += __shfl_xor(Se,  m, 64);
                Sei += __shfl_xor(Sei, m, 64);
                Me   = fmaxf(Me, __shfl_xor(Me, m, 64));
            }
            if (lrow == 0) { red[wn][row][0] = Se; red[wn][row][1] = Sei; red[wn][row][2] = Me; }
        }
    }
    __syncthreads();
    if (t < 64) {
        const int row = t;
        float Se = 0.f, Sei = 0.f, Me = 0.f;
        #pragma unroll
        for (int q = 0; q < 8; ++q) {
            Se += red[q][row][0]; Sei += red[q][row][1]; Me = fmaxf(Me, red[q][row][2]);
        }
        const int w1g = w1base + row;
        const float corresp = Sei / Se;
        const float conf    = Me / Se;
        float disp = fabsf(corresp - (float)w1g) * (1.0f / 512.0f);
        disp = fmaxf(disp, 0.1f);
        const float fx = intri1[b * 9];
        const float dx = extri1[b * 16 + 3]  - extri2[b * 16 + 3];
        const float dy = extri1[b * 16 + 7]  - extri2[b * 16 + 7];
        const float dz = extri1[b * 16 + 11] - extri2[b * 16 + 11];
        const float bl = sqrtf(dx * dx + dy * dy + dz * dz);
        const int oidx = b * HW + h * W_DIM + w1g;
        out[oidx]          = fx * bl / disp;
        out[2 * HW + oidx] = conf;
    }
}

extern "C" void kernel_launch(void* const* d_in, const int* in_sizes, int n_in,
                              void* d_out, int out_size, void* d_ws, size_t ws_size,
                              hipStream_t stream) {
    const float* img1   = (const float*)d_in[0];
    const float* img2   = (const float*)d_in[1];
    const float* intri1 = (const float*)d_in[2];
    const float* extri1 = (const float*)d_in[4];
    const float* extri2 = (const float*)d_in[5];
    if (ws_size >= WS_NEED) {
        unsigned short* bws = (unsigned short*)d_ws;
        transpose_kernel<<<dim3(8192), dim3(256), 0, stream>>>(img2, bws);
        costvol_kernel<<<dim3(1024), dim3(1024), 0, stream>>>(
            img1, bws, intri1, extri1, extri2, (float*)d_out);
    } else {
        costvol_fallback<<<dim3(2048), dim3(512), 0, stream>>>(
            img1, img2, intri1, extri1, extri2, (float*)d_out);
    }
}